// Round 2
// baseline (1332.688 us; speedup 1.0000x reference)
//
#include <hip/hip_runtime.h>
#include <hip/hip_bf16.h>

// Problem constants
#define BB 512   // batch
#define SS 96    // seq len (= c_in of GCN features, = L of conv)
#define NN 64    // nodes (= conv in-channels)
#define HH 512   // hidden (= conv out-channels)
#define EE 512   // edges per graph (before self-loops)

// ---------------------------------------------------------------------------
// K1: build dense normalized adjacency A[b] (64x64) from edge list.
// A[dst,src] = sum over edges dinv[src]*dinv[dst]; diagonal += dinv[n]^2
// deg counts dst occurrences + 1 (self loop).
// ---------------------------------------------------------------------------
__global__ __launch_bounds__(256) void k_build_A(const int* __restrict__ ei,
                                                 float* __restrict__ Aout) {
    const int b = blockIdx.x;
    const int t = threadIdx.x;
    __shared__ int   deg[NN];
    __shared__ float dinv[NN];
    __shared__ float Asm[NN * NN];

    for (int i = t; i < NN * NN; i += 256) Asm[i] = 0.f;
    if (t < NN) deg[t] = 1;   // self loop
    __syncthreads();

    const int* eb = ei + (size_t)b * 2 * EE;
    for (int e = t; e < EE; e += 256) {
        atomicAdd(&deg[eb[EE + e]], 1);
    }
    __syncthreads();
    if (t < NN) dinv[t] = rsqrtf((float)deg[t]);
    __syncthreads();

    for (int e = t; e < EE; e += 256) {
        int src = eb[e], dst = eb[EE + e];
        atomicAdd(&Asm[dst * NN + src], dinv[src] * dinv[dst]);
    }
    if (t < NN) atomicAdd(&Asm[t * NN + t], dinv[t] * dinv[t]);
    __syncthreads();

    float* Ab = Aout + (size_t)b * NN * NN;
    for (int i = t; i < NN * NN; i += 256) Ab[i] = Asm[i];
}

// ---------------------------------------------------------------------------
// K2: G[b] = A[b] @ X_b^T   -> [64, 96];  G[n,s] = sum_m A[n,m] * x[b,s,m]
// ---------------------------------------------------------------------------
__global__ __launch_bounds__(256) void k_G(const float* __restrict__ Aglob,
                                           const float* __restrict__ x,
                                           float* __restrict__ Gout) {
    const int b = blockIdx.x;
    const int t = threadIdx.x;
    __shared__ float As[NN * 65];   // padded stride 65
    __shared__ float xs[SS * 65];   // xs[s*65+n] = x[b,s,n]

    const float* Ab = Aglob + (size_t)b * NN * NN;
    for (int i = t; i < NN * NN; i += 256) As[(i / NN) * 65 + (i % NN)] = Ab[i];
    const float* xb = x + (size_t)b * SS * NN;
    for (int i = t; i < SS * NN; i += 256) xs[(i / NN) * 65 + (i % NN)] = xb[i];
    __syncthreads();

    float* Gb = Gout + (size_t)b * NN * SS;
    for (int idx = t; idx < NN * SS; idx += 256) {
        int n = idx / SS, s = idx % SS;
        float acc = 0.f;
        #pragma unroll 8
        for (int m = 0; m < NN; ++m) acc += As[n * 65 + m] * xs[s * 65 + m];
        Gb[idx] = acc;
    }
}

// ---------------------------------------------------------------------------
// K3: per graph, fused:
//   H1 = relu(G @ W1^T + b1)   [64,512]   (chunked over H, never leaves LDS)
//   T  = H1 @ W2^T             [64,96]    (accumulated in registers)
//   H2 = A @ T + b2            [64,96]    (written in-place over G buffer)
// ---------------------------------------------------------------------------
__global__ __launch_bounds__(256) void k_gcn(float* __restrict__ Gio,  // in: G, out: H2
                                             const float* __restrict__ W1,
                                             const float* __restrict__ b1,
                                             const float* __restrict__ W2,
                                             const float* __restrict__ b2,
                                             const float* __restrict__ Aglob) {
    const int b = blockIdx.x;
    const int t = threadIdx.x;

    __shared__ float lds[12608];          // 50.4 KB
    float* Gs  = lds;                     // [64][97]  (phase 1)
    float* Q   = lds + 6208;
    float* W1c = Q;                       // [16][97]  = 1552
    float* W2c = Q + 1552;                // [96][17]  = 1632
    float* H1c = Q + 3184;                // [64][17]  = 1088
    float* Ts  = Q;                       // phase 2: [64*96]
    float* As  = lds;                     // phase 2: [64][65]

    const float* Gb = Gio + (size_t)b * NN * SS;
    for (int i = t; i < NN * SS; i += 256) Gs[(i / SS) * 97 + (i % SS)] = Gb[i];

    float acc[24];
    #pragma unroll
    for (int i = 0; i < 24; ++i) acc[i] = 0.f;

    for (int hc = 0; hc < HH; hc += 16) {
        __syncthreads();   // protects Q reuse (and first-iter Gs visibility)
        // stage W1 chunk [16][96] and W2 chunk [96][16]
        for (int i = t; i < 16 * SS; i += 256)
            W1c[(i / SS) * 97 + (i % SS)] = W1[(size_t)(hc + i / SS) * SS + (i % SS)];
        for (int i = t; i < SS * 16; i += 256) {
            int s = i / 16, hh = i % 16;
            W2c[s * 17 + hh] = W2[(size_t)s * HH + hc + hh];
        }
        __syncthreads();
        // H1 chunk: 64x16 outputs
        #pragma unroll
        for (int i = 0; i < 4; ++i) {
            int idx = t + 256 * i;
            int hh = idx & 15, n = idx >> 4;
            float a2 = b1[hc + hh];
            #pragma unroll 8
            for (int s = 0; s < SS; ++s) a2 += Gs[n * 97 + s] * W1c[hh * 97 + s];
            H1c[n * 17 + hh] = fmaxf(a2, 0.f);
        }
        __syncthreads();
        // T += H1c @ W2c^T
        #pragma unroll
        for (int i = 0; i < 24; ++i) {
            int idx = t + 256 * i;
            int n = idx / SS, s = idx % SS;
            float a3 = acc[i];
            #pragma unroll
            for (int hh = 0; hh < 16; ++hh) a3 += H1c[n * 17 + hh] * W2c[s * 17 + hh];
            acc[i] = a3;
        }
    }
    __syncthreads();
    // phase 2: T -> LDS, A -> LDS (overlaying dead buffers)
    #pragma unroll
    for (int i = 0; i < 24; ++i) Ts[t + 256 * i] = acc[i];
    const float* Ab = Aglob + (size_t)b * NN * NN;
    for (int i = t; i < NN * NN; i += 256) As[(i / NN) * 65 + (i % NN)] = Ab[i];
    __syncthreads();
    // H2 = A @ T + b2, written over G buffer
    float* Hb = Gio + (size_t)b * NN * SS;
    #pragma unroll
    for (int i = 0; i < 24; ++i) {
        int idx = t + 256 * i;
        int n = idx / SS, s = idx % SS;
        float a4 = b2[s];
        #pragma unroll 8
        for (int m = 0; m < NN; ++m) a4 += As[n * 65 + m] * Ts[m * SS + s];
        Hb[idx] = a4;
    }
}

// ---------------------------------------------------------------------------
// K4: circular conv1d (k=3) + transpose.
// y[b,s,hc+hh] = sum_{n,k} conv_w[hc+hh, n, k] * H2[b, n, (s+k-1) mod 96]
// grid: (16 h-chunks of 32, B).  block: 256 = 32 h  x 8 s-groups of 12.
// ---------------------------------------------------------------------------
__global__ __launch_bounds__(256) void k_conv(const float* __restrict__ Hin,
                                              const float* __restrict__ cw,
                                              float* __restrict__ out) {
    const int chunk = blockIdx.x;          // 0..15
    const int b = blockIdx.y;
    const int t = threadIdx.x;
    const int hc = chunk * 32;

    __shared__ float wc[32 * 193];         // [32 h][192 (n,k)], padded
    __shared__ float Hp[64 * 98];          // [64 n][98], circular-padded rows

    for (int i = t; i < 32 * 192; i += 256) {
        int hh = i / 192, q = i % 192;
        wc[hh * 193 + q] = cw[(size_t)(hc + hh) * 192 + q];
    }
    const float* Hb = Hin + (size_t)b * NN * SS;
    for (int i = t; i < NN * SS; i += 256) {
        int n = i / SS, s = i % SS;
        Hp[n * 98 + s + 1] = Hb[i];
    }
    if (t < NN) {
        Hp[t * 98 + 0]  = Hb[t * SS + SS - 1];
        Hp[t * 98 + 97] = Hb[t * SS + 0];
    }
    __syncthreads();

    const int hh = t & 31, sg = t >> 5;
    const int sbase = sg * 12;
    float acc[12];
    #pragma unroll
    for (int j = 0; j < 12; ++j) acc[j] = 0.f;

    for (int n = 0; n < NN; ++n) {
        float w0 = wc[hh * 193 + n * 3 + 0];
        float w1 = wc[hh * 193 + n * 3 + 1];
        float w2 = wc[hh * 193 + n * 3 + 2];
        const float* hp = &Hp[n * 98 + sbase];
        #pragma unroll
        for (int j = 0; j < 12; ++j)
            acc[j] += w0 * hp[j] + w1 * hp[j + 1] + w2 * hp[j + 2];
    }

    float* ob = out + (size_t)b * SS * HH;
    #pragma unroll
    for (int j = 0; j < 12; ++j)
        ob[(size_t)(sbase + j) * HH + hc + hh] = acc[j];
}

// ---------------------------------------------------------------------------
extern "C" void kernel_launch(void* const* d_in, const int* in_sizes, int n_in,
                              void* d_out, int out_size, void* d_ws, size_t ws_size,
                              hipStream_t stream) {
    const float* x  = (const float*)d_in[0];
    const int*   ei = (const int*)d_in[1];
    const float* W1 = (const float*)d_in[2];
    const float* b1 = (const float*)d_in[3];
    const float* W2 = (const float*)d_in[4];
    const float* b2 = (const float*)d_in[5];
    const float* cw = (const float*)d_in[6];
    float* out = (float*)d_out;

    float* Abuf = (float*)d_ws;                       // B*64*64 fp32 = 8.4 MB
    float* Gbuf = Abuf + (size_t)BB * NN * NN;        // B*64*96 fp32 = 12.6 MB (G, then H2)

    k_build_A<<<BB, 256, 0, stream>>>(ei, Abuf);
    k_G      <<<BB, 256, 0, stream>>>(Abuf, x, Gbuf);
    k_gcn    <<<BB, 256, 0, stream>>>(Gbuf, W1, b1, W2, b2, Abuf);
    dim3 gc(16, BB);
    k_conv   <<<gc, 256, 0, stream>>>(Gbuf, cw, out);
}

// Round 4
// 212.458 us; speedup vs baseline: 6.2727x; 6.2727x over previous
//
#include <hip/hip_runtime.h>
#include <hip/hip_bf16.h>

// Problem constants
#define BB 512   // batch
#define SS 96    // seq len
#define NN 64    // nodes
#define HH 512   // hidden
#define EE 512   // edges per graph

typedef __attribute__((ext_vector_type(8))) short short8;   // 8 bf16 (4 VGPRs)
typedef __attribute__((ext_vector_type(4))) float f32x4;    // MFMA acc

__device__ __forceinline__ unsigned short f2bf(float f) {
    union { float f; unsigned u; } v; v.f = f;
    return (unsigned short)((v.u + 0x7FFFu + ((v.u >> 16) & 1u)) >> 16);   // RNE
}
__device__ __forceinline__ ushort4 f4bf(float4 v) {
    ushort4 u; u.x = f2bf(v.x); u.y = f2bf(v.y); u.z = f2bf(v.z); u.w = f2bf(v.w);
    return u;
}

// ---------------------------------------------------------------------------
// k_mega: one block per graph. Everything up to H2 stays in LDS.
//   phase 0: dense normalized adjacency A (LDS atomics) -> bf16 As
//   MFMA0:   G = A @ X^T                      [64 n][96 s]  -> Gs (bf16, LDS)
//   loop hc (8 x 64 hidden):
//     MFMA1: H1c = relu(G @ W1c^T + b1c)      [64 n][64 h]  -> H1s (bf16, LDS)
//     MFMA2: T += H1c @ W2c^T                 [64 n][96 s]  (regs)
//   MFMA3:   H2 = A @ T + b2 -> H2T[s][n] bf16 (global, 12 KB/graph)
// LDS overlays (59392 B total, 2 blocks/CU):
//   As    @0      [64][72] u16          (whole kernel)
//   XsW2  @9216   [96][72] u16          (Xs in phase G, W2s in loop)
//   Gs    @23040  [64][104] u16         (phase G + loop)
//   W1sT  @36352  [64][104] u16 as W1s; [96][72] as TsT (tail spills into dead H1s)
//   Asm   @36352  [64][64] f32          (phase 0 only)
//   H1s   @49664  [64][72] u16          (loop)
//   deg   @58880, dinv @59136
// ---------------------------------------------------------------------------
__global__ __launch_bounds__(256) void k_mega(const float* __restrict__ x,
                                              const int* __restrict__ ei,
                                              const float* __restrict__ W1,
                                              const float* __restrict__ b1,
                                              const float* __restrict__ W2,
                                              const float* __restrict__ b2,
                                              unsigned short* __restrict__ H2T) {
    const int b = blockIdx.x, t = threadIdx.x;
    const int wave = t >> 6, lane = t & 63, quad = lane >> 4, l16 = lane & 15;

    __shared__ __align__(16) char smem[59392];
    unsigned short* As   = (unsigned short*)smem;
    unsigned short* XsW2 = (unsigned short*)(smem + 9216);
    unsigned short* Gs   = (unsigned short*)(smem + 23040);
    unsigned short* W1sT = (unsigned short*)(smem + 36352);
    float*          Asm  = (float*)(smem + 36352);
    unsigned short* H1s  = (unsigned short*)(smem + 49664);
    int*            deg  = (int*)(smem + 58880);
    float*          dinv = (float*)(smem + 59136);

    // ---- phase 0: adjacency ----
    for (int i = t; i < 4096; i += 256) Asm[i] = 0.f;
    if (t < NN) deg[t] = 1;                       // self loop
    __syncthreads();
    const int* eb = ei + (size_t)b * 2 * EE;
    for (int e = t; e < EE; e += 256) atomicAdd(&deg[eb[EE + e]], 1);
    __syncthreads();
    if (t < NN) dinv[t] = rsqrtf((float)deg[t]);
    __syncthreads();
    for (int e = t; e < EE; e += 256) {
        int s = eb[e], d = eb[EE + e];
        atomicAdd(&Asm[d * 64 + s], dinv[s] * dinv[d]);
    }
    if (t < NN) atomicAdd(&Asm[t * 64 + t], dinv[t] * dinv[t]);
    __syncthreads();

    // As (bf16) <- Asm ; Xs (bf16) <- x[b]  (disjoint LDS regions)
    for (int i = t; i < 1024; i += 256) {
        int n = i >> 4, m4 = (i & 15) * 4;
        *(ushort4*)(As + n * 72 + m4) = f4bf(*(const float4*)(Asm + n * 64 + m4));
    }
    const float* xb = x + (size_t)b * SS * NN;
    for (int i = t; i < 96 * 16; i += 256) {
        int s = i >> 4, c4 = (i & 15) * 4;
        *(ushort4*)(XsW2 + s * 72 + c4) = f4bf(*(const float4*)(xb + s * 64 + c4));
    }
    __syncthreads();

    // ---- MFMA0: G[n][s] = A @ X^T ----
    {
        short8 a0 = *(const short8*)(As + (wave * 16 + l16) * 72 + quad * 8);
        short8 a1 = *(const short8*)(As + (wave * 16 + l16) * 72 + 32 + quad * 8);
        f32x4 acc0[6];
        #pragma unroll
        for (int j = 0; j < 6; ++j) acc0[j] = (f32x4){0.f, 0.f, 0.f, 0.f};
        #pragma unroll
        for (int j = 0; j < 6; ++j) {
            short8 bb0 = *(const short8*)(XsW2 + (j * 16 + l16) * 72 + quad * 8);
            short8 bb1 = *(const short8*)(XsW2 + (j * 16 + l16) * 72 + 32 + quad * 8);
            acc0[j] = __builtin_amdgcn_mfma_f32_16x16x32_bf16(a0, bb0, acc0[j], 0, 0, 0);
            acc0[j] = __builtin_amdgcn_mfma_f32_16x16x32_bf16(a1, bb1, acc0[j], 0, 0, 0);
        }
        #pragma unroll
        for (int j = 0; j < 6; ++j)
            #pragma unroll
            for (int r = 0; r < 4; ++r)
                Gs[(wave * 16 + quad * 4 + r) * 104 + j * 16 + l16] = f2bf(acc0[j][r]);
    }

    // ---- hidden-chunk loop ----
    f32x4 accT[6];
    #pragma unroll
    for (int j = 0; j < 6; ++j) accT[j] = (f32x4){0.f, 0.f, 0.f, 0.f};

    for (int hc = 0; hc < 8; ++hc) {
        __syncthreads();   // prev MFMA2 reads (XsW2,H1s) + MFMA0 Xs reads / Gs writes
        for (int i = t; i < 64 * 24; i += 256) {           // W1s [64 h][96 s]
            int row = i / 24, c4 = (i % 24) * 4;
            *(ushort4*)(W1sT + row * 104 + c4) =
                f4bf(*(const float4*)(W1 + (size_t)(hc * 64 + row) * 96 + c4));
        }
        for (int i = t; i < 96 * 16; i += 256) {           // W2s [96 s][64 h]
            int row = i >> 4, c4 = (i & 15) * 4;
            *(ushort4*)(XsW2 + row * 72 + c4) =
                f4bf(*(const float4*)(W2 + (size_t)row * HH + hc * 64 + c4));
        }
        __syncthreads();
        // MFMA1: H1c = relu(G @ W1c^T + b1c)
        short8 ga[3];
        #pragma unroll
        for (int kc = 0; kc < 3; ++kc)
            ga[kc] = *(const short8*)(Gs + (wave * 16 + l16) * 104 + kc * 32 + quad * 8);
        f32x4 acc1[4];
        #pragma unroll
        for (int j = 0; j < 4; ++j) acc1[j] = (f32x4){0.f, 0.f, 0.f, 0.f};
        #pragma unroll
        for (int j = 0; j < 4; ++j)
            #pragma unroll
            for (int kc = 0; kc < 3; ++kc) {
                short8 bb = *(const short8*)(W1sT + (j * 16 + l16) * 104 + kc * 32 + quad * 8);
                acc1[j] = __builtin_amdgcn_mfma_f32_16x16x32_bf16(ga[kc], bb, acc1[j], 0, 0, 0);
            }
        float bias[4];
        #pragma unroll
        for (int j = 0; j < 4; ++j) bias[j] = b1[hc * 64 + j * 16 + l16];
        #pragma unroll
        for (int j = 0; j < 4; ++j)
            #pragma unroll
            for (int r = 0; r < 4; ++r)
                H1s[(wave * 16 + quad * 4 + r) * 72 + j * 16 + l16] =
                    f2bf(fmaxf(acc1[j][r] + bias[j], 0.f));
        __syncthreads();
        // MFMA2: T += H1c @ W2c^T
        short8 ha0 = *(const short8*)(H1s + (wave * 16 + l16) * 72 + quad * 8);
        short8 ha1 = *(const short8*)(H1s + (wave * 16 + l16) * 72 + 32 + quad * 8);
        #pragma unroll
        for (int j = 0; j < 6; ++j) {
            short8 bb0 = *(const short8*)(XsW2 + (j * 16 + l16) * 72 + quad * 8);
            short8 bb1 = *(const short8*)(XsW2 + (j * 16 + l16) * 72 + 32 + quad * 8);
            accT[j] = __builtin_amdgcn_mfma_f32_16x16x32_bf16(ha0, bb0, accT[j], 0, 0, 0);
            accT[j] = __builtin_amdgcn_mfma_f32_16x16x32_bf16(ha1, bb1, accT[j], 0, 0, 0);
        }
    }
    __syncthreads();   // drain last MFMA2 LDS reads (TsT tail overlaps H1s rows 0-3)

    // TsT[s][m] = T (bf16) into W1s region
    #pragma unroll
    for (int j = 0; j < 6; ++j)
        #pragma unroll
        for (int r = 0; r < 4; ++r)
            W1sT[(j * 16 + l16) * 72 + wave * 16 + quad * 4 + r] = f2bf(accT[j][r]);
    __syncthreads();

    // ---- MFMA3: H2 = A @ T + b2 -> H2T[s][n] bf16 ----
    {
        short8 a0 = *(const short8*)(As + (wave * 16 + l16) * 72 + quad * 8);
        short8 a1 = *(const short8*)(As + (wave * 16 + l16) * 72 + 32 + quad * 8);
        f32x4 acc3[6];
        #pragma unroll
        for (int j = 0; j < 6; ++j) acc3[j] = (f32x4){0.f, 0.f, 0.f, 0.f};
        #pragma unroll
        for (int j = 0; j < 6; ++j) {
            short8 t0 = *(const short8*)(W1sT + (j * 16 + l16) * 72 + quad * 8);
            short8 t1 = *(const short8*)(W1sT + (j * 16 + l16) * 72 + 32 + quad * 8);
            acc3[j] = __builtin_amdgcn_mfma_f32_16x16x32_bf16(a0, t0, acc3[j], 0, 0, 0);
            acc3[j] = __builtin_amdgcn_mfma_f32_16x16x32_bf16(a1, t1, acc3[j], 0, 0, 0);
        }
        unsigned short* Hb = H2T + (size_t)b * SS * NN;
        #pragma unroll
        for (int j = 0; j < 6; ++j) {
            float bb2 = b2[j * 16 + l16];            // s = j*16+l16
            #pragma unroll
            for (int r = 0; r < 4; ++r)
                Hb[(j * 16 + l16) * NN + wave * 16 + quad * 4 + r] = f2bf(acc3[j][r] + bb2);
        }
    }
}

// ---------------------------------------------------------------------------
// k_conv: conv as bf16 MFMA GEMM per graph: y[h][s] = sum_{kw,n} W'[h][kw*64+n]
//     * H2T[(s+kw-1)%96][n].  Grid (8 h-blocks of 64, B). 4 waves: wave = 16 h.
// ---------------------------------------------------------------------------
__global__ __launch_bounds__(256) void k_conv(const unsigned short* __restrict__ H2T,
                                              const float* __restrict__ cw,
                                              float* __restrict__ out) {
    const int hb = blockIdx.x, b = blockIdx.y, t = threadIdx.x;
    const int wave = t >> 6, lane = t & 63, quad = lane >> 4, l16 = lane & 15;
    const int h0 = hb * 64;

    __shared__ __align__(16) unsigned short Wc[64 * 200];   // [h][kw*64+n]
    __shared__ __align__(16) unsigned short Hp[98 * 72];    // [sp = s+1][n]

    for (int i = t; i < 64 * 48; i += 256) {
        int row = i / 48, c4 = (i % 48) * 4;
        float4 v = *(const float4*)(cw + (size_t)(h0 + row) * 192 + c4);
        float vv[4] = {v.x, v.y, v.z, v.w};
        #pragma unroll
        for (int q = 0; q < 4; ++q) {
            int kap = c4 + q, n = kap / 3, kw = kap % 3;
            Wc[row * 200 + kw * 64 + n] = f2bf(vv[q]);
        }
    }
    const unsigned short* Hsrc = H2T + (size_t)b * SS * NN;
    for (int i = t; i < 98 * 8; i += 256) {
        int sp = i >> 3, c8 = (i & 7) * 8;
        int s = (sp == 0) ? 95 : ((sp == 97) ? 0 : sp - 1);
        *(short8*)(Hp + sp * 72 + c8) = *(const short8*)(Hsrc + s * NN + c8);
    }
    __syncthreads();

    short8 a[6];
    #pragma unroll
    for (int kc = 0; kc < 6; ++kc)
        a[kc] = *(const short8*)(Wc + (wave * 16 + l16) * 200 + kc * 32 + quad * 8);

    f32x4 acc[6];
    #pragma unroll
    for (int j = 0; j < 6; ++j) acc[j] = (f32x4){0.f, 0.f, 0.f, 0.f};

    #pragma unroll
    for (int j = 0; j < 6; ++j) {
        #pragma unroll
        for (int kc = 0; kc < 6; ++kc) {
            int kw = kc >> 1, nb = (kc & 1) * 32;
            int sp = j * 16 + l16 + kw;
            short8 bf = *(const short8*)(Hp + sp * 72 + nb + quad * 8);
            acc[j] = __builtin_amdgcn_mfma_f32_16x16x32_bf16(a[kc], bf, acc[j], 0, 0, 0);
        }
    }

    float* ob = out + (size_t)b * SS * HH;
    #pragma unroll
    for (int j = 0; j < 6; ++j)
        #pragma unroll
        for (int r = 0; r < 4; ++r)
            ob[(size_t)(j * 16 + l16) * HH + h0 + wave * 16 + quad * 4 + r] = acc[j][r];
}

// ---------------------------------------------------------------------------
extern "C" void kernel_launch(void* const* d_in, const int* in_sizes, int n_in,
                              void* d_out, int out_size, void* d_ws, size_t ws_size,
                              hipStream_t stream) {
    const float* x  = (const float*)d_in[0];
    const int*   ei = (const int*)d_in[1];
    const float* W1 = (const float*)d_in[2];
    const float* b1 = (const float*)d_in[3];
    const float* W2 = (const float*)d_in[4];
    const float* b2 = (const float*)d_in[5];
    const float* cw = (const float*)d_in[6];
    float* out = (float*)d_out;

    unsigned short* H2T = (unsigned short*)d_ws;   // 512*96*64 bf16 = 6.3 MB only

    k_mega<<<BB, 256, 0, stream>>>(x, ei, W1, b1, W2, b2, H2T);
    dim3 gc(8, BB);
    k_conv<<<gc, 256, 0, stream>>>(H2T, cw, out);
}